// Round 11
// baseline (354.248 us; speedup 1.0000x reference)
//
#include <hip/hip_runtime.h>

#define NC 64      // channels / signal dim
#define NA 512     // dictionary atoms
#define KS 5       // sparsity

// ---- workspace layout in DOUBLES ----
#define WS_DN   0        // Dn_f64 [NC][NA]   (for gram)
#define WS_DNT  32768    // DnT    [NA][NC]   (for epilogue reconstruction)
#define WS_G    65536    // G      [NA][NA]
#define WS_DEN  327680   // den    [NA]
#define WS_ACC  328192   // loss accumulator

// out layout (FLOAT32): z_dl[2097152] | loss[1] | support[163840] | coeffs[163840]
#define OUT_LOSS 2097152
#define OUT_SUP  2097153
#define OUT_COF  2260993

__global__ void norm_kernel(const float* __restrict__ D, double* __restrict__ Dn,
                            double* __restrict__ DnT, double* __restrict__ den) {
  int n = blockIdx.x * blockDim.x + threadIdx.x;
  if (n >= NA) return;
  double s = 0.0;
  for (int c = 0; c < NC; ++c) {
    double v = (double)D[c * NA + n];
    s += v * v;
  }
  double dd = fmax(sqrt(s), 1e-10);
  den[n] = dd;
  for (int c = 0; c < NC; ++c) {
    double v = (double)D[c * NA + n] / dd;
    Dn[c * NA + n]  = v;
    DnT[n * NC + c] = v;
  }
}

__global__ void gram_kernel(const double* __restrict__ Dn,
                            double* __restrict__ G, double* __restrict__ accum) {
  __shared__ double col[NC];
  int i = blockIdx.x, t = threadIdx.x;
  if (t < NC) col[t] = Dn[t * NA + i];
  if (i == 0 && t == 0) *accum = 0.0;
  __syncthreads();
  double s = 0.0;
#pragma unroll
  for (int c = 0; c < NC; ++c) s += col[c] * Dn[c * NA + t];
  G[(size_t)i * NA + t] = s;
}

// One OMP iteration, compile-time step index KK (all private indices literal).
// Lane owns atom pairs: slot s (0..7) <-> atom a = (s>>1)*128 + 2*lane + (s&1).
template<int KK>
__device__ __forceinline__ void omp_step(
    const int lane, const double* __restrict__ G, const double (&a8)[8],
    double (&h8)[8], unsigned &msk, int (&I)[KS],
    double (&Lm)[15], double (&rd)[KS], double (&gam)[KS], double (&hbI)[KS]) {
  // argmax |h|*mask; first-occurrence (smallest global index) tie-break
  double bv = -1.0; int bn = 0;
#pragma unroll
  for (int s = 0; s < 8; ++s) {
    int a = ((s >> 1) << 7) + 2 * lane + (s & 1);
    double v = ((msk >> s) & 1u) ? fabs(h8[s]) : 0.0;
    if (v > bv || (v == bv && a < bn)) { bv = v; bn = a; }
  }
#pragma unroll
  for (int off = 1; off < 64; off <<= 1) {
    double ov = __shfl_xor(bv, off);
    int    on = __shfl_xor(bn, off);
    if (ov > bv || (ov == bv && on < bn)) { bv = ov; bn = on; }
  }
  const int idx = bn;                              // wave-uniform
  if (((idx & 127) >> 1) == lane)
    msk &= ~(1u << (((idx >> 7) << 1) | (idx & 1)));

  // h_bar[idx]: uniform-slot select from owner's registers + broadcast shuffle
  {
    const int su = ((idx >> 7) << 1) | (idx & 1);  // wave-uniform slot
    double v = a8[0];
    if (su == 1) v = a8[1]; if (su == 2) v = a8[2]; if (su == 3) v = a8[3];
    if (su == 4) v = a8[4]; if (su == 5) v = a8[5]; if (su == 6) v = a8[6];
    if (su == 7) v = a8[7];
    hbI[KK] = __shfl(v, (idx & 127) >> 1);
  }
  I[KK] = idx;

  // Cholesky update (replicated on all lanes; reciprocal-diag solves)
  if constexpr (KK == 0) {
    Lm[0] = 1.0; rd[0] = 1.0;
  } else {
    double Gc[KK], w_[KK];
#pragma unroll
    for (int j = 0; j < KK; ++j) Gc[j] = G[(size_t)I[j] * NA + idx];
#pragma unroll
    for (int i = 0; i < KK; ++i) {
      double ssum = Gc[i];
#pragma unroll
      for (int j = 0; j < i; ++j) ssum -= Lm[i*(i+1)/2 + j] * w_[j];
      w_[i] = ssum * rd[i];
    }
    double ww = 0.0;
#pragma unroll
    for (int i = 0; i < KK; ++i) ww += w_[i] * w_[i];
    double corner = sqrt(fmax(1.0 - ww, 1e-12));
#pragma unroll
    for (int j = 0; j < KK; ++j) Lm[KK*(KK+1)/2 + j] = w_[j];
    Lm[KK*(KK+1)/2 + KK] = corner;
    rd[KK] = 1.0 / corner;
  }

  // gamma = cho_solve((L, lower), h_bar[I]) at size KK+1
  double y[KK + 1];
#pragma unroll
  for (int i = 0; i <= KK; ++i) {
    double b_ = hbI[i];
#pragma unroll
    for (int j = 0; j < i; ++j) b_ -= Lm[i*(i+1)/2 + j] * y[j];
    y[i] = b_ * rd[i];
  }
#pragma unroll
  for (int i = KK; i >= 0; --i) {
    double g_ = y[i];
#pragma unroll
    for (int j = i + 1; j <= KK; ++j) g_ -= Lm[j*(j+1)/2 + i] * gam[j];
    gam[i] = g_ * rd[i];
  }

  // h = h_bar - sum_j gam_j * G[I_j]  (base from regs, rows streamed from L2)
  if constexpr (KK < 4) {
#pragma unroll
    for (int s = 0; s < 8; ++s) h8[s] = a8[s];
#pragma unroll
    for (int j = 0; j <= KK; ++j) {
      const double2* g2 = (const double2*)(G + (size_t)I[j] * NA);
      const double gj = gam[j];
#pragma unroll
      for (int i = 0; i < 4; ++i) {
        double2 g = g2[(i << 6) + lane];
        h8[i * 2]     -= gj * g.x;
        h8[i * 2 + 1] -= gj * g.y;
      }
    }
  }
}

// 8 signals per block (2 per wave), grid 4096.  LDS ~18.3 KB.
__global__ __launch_bounds__(256, 2) void omp_kernel(
    const float* __restrict__ z, const float* __restrict__ Draw,
    const double* __restrict__ DnT, const double* __restrict__ G,
    const double* __restrict__ den, float* __restrict__ out,
    double* __restrict__ accum) {
  __shared__ float fstage[8 * NA];   // 16 KB: f32 D-chunk staging
  __shared__ float xsz[8 * NC];      // 2 KB: xs[s][c] first, zout[c][s] later
  __shared__ double wsq[8];
  const int t = threadIdx.x, lane = t & 63, wv = t >> 6;
  const int m0 = blockIdx.x * 8;
  const int bh = m0 >> 6, b = bh >> 6, h = bh & 63, w0 = m0 & 63;
  const size_t zbase = (size_t)b * 262144 + (size_t)h * 64 + w0;

  // load 8 signals coalesced into xs (xsz[s*64+c])
  for (int j = t; j < 8 * NC; j += 256) {
    int c = j >> 3, s = j & 7;
    xsz[s * NC + c] = z[zbase + (size_t)c * 4096 + s];
  }
  __syncthreads();
  // per-lane copy: lane holds channel=lane value of its wave's two signals
  const float xf0 = xsz[(wv * 2 + 0) * NC + lane];
  const float xf1 = xsz[(wv * 2 + 1) * NC + lane];

  // ---- phase 1: h_bar GEMM. acc_f64 += f64(x_f32)*f64(D_f32) (exact), /den at end.
  double acc[2][8];
#pragma unroll
  for (int s = 0; s < 2; ++s)
#pragma unroll
    for (int i = 0; i < 8; ++i) acc[s][i] = 0.0;

  const float4* D4 = (const float4*)Draw;
  float4* st4 = (float4*)fstage;
  for (int ch = 0; ch < 8; ++ch) {
    if (ch) __syncthreads();               // previous chunk fully consumed
#pragma unroll
    for (int p = 0; p < 4; ++p)            // 1024 float4 per 8-row chunk
      st4[p * 256 + t] = D4[ch * 1024 + p * 256 + t];
    __syncthreads();
#pragma unroll
    for (int c8 = 0; c8 < 8; ++c8) {
      const int c = ch * 8 + c8;
      const double x0 = (double)__shfl(xf0, c);
      const double x1 = (double)__shfl(xf1, c);
      const float2* row2 = (const float2*)(fstage + c8 * NA);
#pragma unroll
      for (int i = 0; i < 4; ++i) {
        float2 dv = row2[(i << 6) + lane];
        const double d0 = (double)dv.x, d1 = (double)dv.y;
        acc[0][i * 2] += x0 * d0; acc[0][i * 2 + 1] += x0 * d1;
        acc[1][i * 2] += x1 * d0; acc[1][i * 2 + 1] += x1 * d1;
      }
    }
  }
  // divide by den (true division, matching ref's Dn = D/den up to 1e-15)
#pragma unroll
  for (int i = 0; i < 4; ++i) {
    double2 dn2 = ((const double2*)den)[(i << 6) + lane];
    acc[0][i * 2] /= dn2.x; acc[0][i * 2 + 1] /= dn2.y;
    acc[1][i * 2] /= dn2.x; acc[1][i * 2 + 1] /= dn2.y;
  }

  // ---- phase 2: OMP, one wave per signal (2 sequential per wave), no barriers
#pragma unroll
  for (int si = 0; si < 2; ++si) {
    const int sig = wv * 2 + si, m = m0 + sig;
    const double (&a8)[8] = (si == 0) ? acc[0] : acc[1];
    double h8[8];
#pragma unroll
    for (int i = 0; i < 8; ++i) h8[i] = a8[i];
    unsigned msk = 0xFFu;
    int I[KS];
    double Lm[15], rd[KS], gam[KS], hbI[KS];

    omp_step<0>(lane, G, a8, h8, msk, I, Lm, rd, gam, hbI);
    omp_step<1>(lane, G, a8, h8, msk, I, Lm, rd, gam, hbI);
    omp_step<2>(lane, G, a8, h8, msk, I, Lm, rd, gam, hbI);
    omp_step<3>(lane, G, a8, h8, msk, I, Lm, rd, gam, hbI);
    omp_step<4>(lane, G, a8, h8, msk, I, Lm, rd, gam, hbI);

    // ---- epilogue for this signal
    double r = 0.0;
#pragma unroll
    for (int j = 0; j < KS; ++j) r += gam[j] * DnT[(size_t)I[j] * NC + lane];
    const double e = (double)((si == 0) ? xf0 : xf1);
    const double d = r - e;                      // z_dl - z_e
    xsz[lane * 8 + sig] = (float)(e + d);        // zout[c=lane][s=sig]
    double sq = d * d;
#pragma unroll
    for (int off = 1; off < 64; off <<= 1) sq += __shfl_xor(sq, off);
    if (lane == 0) wsq[sig] = sq;

    // support / coeffs: constant-index selection chains only
    if (lane < KS) {
      int    iv = I[0];
      double gv = gam[0];
      if (lane == 1) { iv = I[1]; gv = gam[1]; }
      if (lane == 2) { iv = I[2]; gv = gam[2]; }
      if (lane == 3) { iv = I[3]; gv = gam[3]; }
      if (lane == 4) { iv = I[4]; gv = gam[4]; }
      out[OUT_SUP + (size_t)m * KS + lane] = (float)iv;
      out[OUT_COF + (size_t)m * KS + lane] = (float)gv;
    }
  }

  __syncthreads();
  // coalesced z_dl store from zout (xsz[c*8+s] == xsz[j])
  for (int j = t; j < 8 * NC; j += 256) {
    int c = j >> 3, s = j & 7;
    out[zbase + (size_t)c * 4096 + s] = xsz[j];
  }
  if (t == 0) {
    double ssum = 0.0;
#pragma unroll
    for (int i = 0; i < 8; ++i) ssum += wsq[i];
    atomicAdd(accum, ssum);
  }
}

__global__ void final_kernel(const double* __restrict__ accum, float* __restrict__ out) {
  double mse = *accum / 2097152.0;
  out[OUT_LOSS] = (float)(mse + 0.25 * mse);
}

extern "C" void kernel_launch(void* const* d_in, const int* in_sizes, int n_in,
                              void* d_out, int out_size, void* d_ws, size_t ws_size,
                              hipStream_t stream) {
  const float* z_e = (const float*)d_in[0];
  const float* dic = (const float*)d_in[1];
  float* out = (float*)d_out;
  double* ws = (double*)d_ws;
  double* Dn   = ws + WS_DN;
  double* DnT  = ws + WS_DNT;
  double* G    = ws + WS_G;
  double* den  = ws + WS_DEN;
  double* accu = ws + WS_ACC;

  hipLaunchKernelGGL(norm_kernel,  dim3(1),    dim3(512), 0, stream, dic, Dn, DnT, den);
  hipLaunchKernelGGL(gram_kernel,  dim3(NA),   dim3(NA),  0, stream, Dn, G, accu);
  hipLaunchKernelGGL(omp_kernel,   dim3(4096), dim3(256), 0, stream,
                     z_e, dic, DnT, G, den, out, accu);
  hipLaunchKernelGGL(final_kernel, dim3(1),    dim3(1),   0, stream, accu, out);
}

// Round 12
// 246.712 us; speedup vs baseline: 1.4359x; 1.4359x over previous
//
#include <hip/hip_runtime.h>

#define NC 64      // channels / signal dim
#define NA 512     // dictionary atoms
#define KS 5       // sparsity

// ---- workspace layout in DOUBLES ----
#define WS_DN   0        // Dn_f64 [NC][NA]   (for gram)
#define WS_DNT  32768    // DnT    [NA][NC]   (for epilogue reconstruction)
#define WS_G    65536    // G      [NA][NA]
#define WS_RDEN 327680   // 1/den  [NA]
#define WS_ACC  328192   // loss accumulator

// out layout (FLOAT32): z_dl[2097152] | loss[1] | support[163840] | coeffs[163840]
#define OUT_LOSS 2097152
#define OUT_SUP  2097153
#define OUT_COF  2260993

__global__ void norm_kernel(const float* __restrict__ D, double* __restrict__ Dn,
                            double* __restrict__ DnT, double* __restrict__ rden) {
  int n = blockIdx.x * blockDim.x + threadIdx.x;
  if (n >= NA) return;
  double s = 0.0;
  for (int c = 0; c < NC; ++c) {
    double v = (double)D[c * NA + n];
    s += v * v;
  }
  double dd = fmax(sqrt(s), 1e-10);
  rden[n] = 1.0 / dd;
  for (int c = 0; c < NC; ++c) {
    double v = (double)D[c * NA + n] / dd;
    Dn[c * NA + n]  = v;
    DnT[n * NC + c] = v;
  }
}

__global__ void gram_kernel(const double* __restrict__ Dn,
                            double* __restrict__ G, double* __restrict__ accum) {
  __shared__ double col[NC];
  int i = blockIdx.x, t = threadIdx.x;
  if (t < NC) col[t] = Dn[t * NA + i];
  if (i == 0 && t == 0) *accum = 0.0;
  __syncthreads();
  double s = 0.0;
#pragma unroll
  for (int c = 0; c < NC; ++c) s += col[c] * Dn[c * NA + t];
  G[(size_t)i * NA + t] = s;
}

// One OMP iteration, compile-time step index KK (all private indices literal ->
// SROA keeps state in VGPRs; h_bar lives in LDS, no register lifetime hazards).
// Lane owns atom pairs: slot s (0..7) <-> atom a = (s>>1)*128 + 2*lane + (s&1).
template<int KK>
__device__ __forceinline__ void omp_step(
    const int lane, const double* __restrict__ G,
    const double* __restrict__ hbs, const double2* __restrict__ hb2,
    double (&h8)[8], unsigned &msk, int (&I)[KS],
    double (&Lm)[15], double (&rd)[KS], double (&gam)[KS], double (&hbI)[KS]) {
  // argmax |h|*mask; first-occurrence (smallest global index) tie-break
  double bv = -1.0; int bn = 0;
#pragma unroll
  for (int s = 0; s < 8; ++s) {
    int a = ((s >> 1) << 7) + 2 * lane + (s & 1);
    double v = ((msk >> s) & 1u) ? fabs(h8[s]) : 0.0;
    if (v > bv || (v == bv && a < bn)) { bv = v; bn = a; }
  }
#pragma unroll
  for (int off = 1; off < 64; off <<= 1) {
    double ov = __shfl_xor(bv, off);
    int    on = __shfl_xor(bn, off);
    if (ov > bv || (ov == bv && on < bn)) { bv = ov; bn = on; }
  }
  const int idx = bn;                              // wave-uniform
  if (((idx & 127) >> 1) == lane)
    msk &= ~(1u << (((idx >> 7) << 1) | (idx & 1)));

  hbI[KK] = hbs[idx];                              // LDS broadcast read
  I[KK] = idx;

  // Cholesky update (replicated on all lanes; reciprocal-diag solves)
  if constexpr (KK == 0) {
    Lm[0] = 1.0; rd[0] = 1.0;
  } else {
    double Gc[KK], w_[KK];
#pragma unroll
    for (int j = 0; j < KK; ++j) Gc[j] = G[(size_t)I[j] * NA + idx];
#pragma unroll
    for (int i = 0; i < KK; ++i) {
      double ssum = Gc[i];
#pragma unroll
      for (int j = 0; j < i; ++j) ssum -= Lm[i*(i+1)/2 + j] * w_[j];
      w_[i] = ssum * rd[i];
    }
    double ww = 0.0;
#pragma unroll
    for (int i = 0; i < KK; ++i) ww += w_[i] * w_[i];
    double corner = sqrt(fmax(1.0 - ww, 1e-12));
#pragma unroll
    for (int j = 0; j < KK; ++j) Lm[KK*(KK+1)/2 + j] = w_[j];
    Lm[KK*(KK+1)/2 + KK] = corner;
    rd[KK] = 1.0 / corner;
  }

  // gamma = cho_solve((L, lower), h_bar[I]) at size KK+1
  double y[KK + 1];
#pragma unroll
  for (int i = 0; i <= KK; ++i) {
    double b_ = hbI[i];
#pragma unroll
    for (int j = 0; j < i; ++j) b_ -= Lm[i*(i+1)/2 + j] * y[j];
    y[i] = b_ * rd[i];
  }
#pragma unroll
  for (int i = KK; i >= 0; --i) {
    double g_ = y[i];
#pragma unroll
    for (int j = i + 1; j <= KK; ++j) g_ -= Lm[j*(j+1)/2 + i] * gam[j];
    gam[i] = g_ * rd[i];
  }

  // h = h_bar - sum_j gam_j * G[I_j]  (base from LDS park, rows streamed from L2)
  if constexpr (KK < 4) {
#pragma unroll
    for (int i = 0; i < 4; ++i) {
      double2 hv = hb2[(i << 6) + lane];
      h8[i * 2] = hv.x; h8[i * 2 + 1] = hv.y;
    }
#pragma unroll
    for (int j = 0; j <= KK; ++j) {
      const double2* g2 = (const double2*)(G + (size_t)I[j] * NA);
      const double gj = gam[j];
#pragma unroll
      for (int i = 0; i < 4; ++i) {
        double2 g = g2[(i << 6) + lane];
        h8[i * 2]     -= gj * g.x;
        h8[i * 2 + 1] -= gj * g.y;
      }
    }
  }
}

union __align__(16) StageBuf {
  float  f[8 * NA];    // 16 KB view: f32 D-chunk staging (phase 1)
  double d[8 * NA];    // 32 KB view: parked h_bar[8][512]  (phase 2)
};

// 8 signals per block (2 per wave), grid 4096.  LDS ~34.2 KB -> 4 blocks/CU.
__global__ __launch_bounds__(256, 2) void omp_kernel(
    const float* __restrict__ z, const float* __restrict__ Draw,
    const double* __restrict__ DnT, const double* __restrict__ G,
    const double* __restrict__ rden, float* __restrict__ out,
    double* __restrict__ accum) {
  __shared__ StageBuf buf;
  __shared__ float xsz[8 * NC];      // 2 KB: xs[s][c] first, zout[c][s] later
  __shared__ double wsq[8];
  const int t = threadIdx.x, lane = t & 63, wv = t >> 6;
  const int m0 = blockIdx.x * 8;
  const int bh = m0 >> 6, b = bh >> 6, h = bh & 63, w0 = m0 & 63;
  const size_t zbase = (size_t)b * 262144 + (size_t)h * 64 + w0;

  // load 8 signals coalesced into xs (xsz[s*64+c])
  for (int j = t; j < 8 * NC; j += 256) {
    int c = j >> 3, s = j & 7;
    xsz[s * NC + c] = z[zbase + (size_t)c * 4096 + s];
  }
  __syncthreads();
  // per-lane copy: lane holds channel=lane value of its wave's two signals
  const float xf0 = xsz[(wv * 2 + 0) * NC + lane];
  const float xf1 = xsz[(wv * 2 + 1) * NC + lane];
  // xsz free from here (zout reuses it)

  // ---- phase 1: h_bar GEMM. acc_f64 += f64(x_f32)*f64(D_f32) (exact);
  //      scaled by 1/den at parking (matches ref Dn=D/den to ~2 ulp).
  {
    double acc[2][8];
#pragma unroll
    for (int s = 0; s < 2; ++s)
#pragma unroll
      for (int i = 0; i < 8; ++i) acc[s][i] = 0.0;

    const float4* D4 = (const float4*)Draw;
    float4* st4 = (float4*)buf.f;
    for (int ch = 0; ch < 8; ++ch) {
      if (ch) __syncthreads();             // previous chunk fully consumed
#pragma unroll
      for (int p = 0; p < 4; ++p)          // 1024 float4 per 8-row chunk
        st4[p * 256 + t] = D4[ch * 1024 + p * 256 + t];
      __syncthreads();
#pragma unroll
      for (int c8 = 0; c8 < 8; ++c8) {
        const int c = ch * 8 + c8;
        const double x0 = (double)__shfl(xf0, c);
        const double x1 = (double)__shfl(xf1, c);
        const float2* row2 = (const float2*)(buf.f + c8 * NA);
#pragma unroll
        for (int i = 0; i < 4; ++i) {
          float2 dv = row2[(i << 6) + lane];
          const double d0 = (double)dv.x, d1 = (double)dv.y;
          acc[0][i * 2] += x0 * d0; acc[0][i * 2 + 1] += x0 * d1;
          acc[1][i * 2] += x1 * d0; acc[1][i * 2 + 1] += x1 * d1;
        }
      }
    }
    __syncthreads();                       // all waves done reading f32 stage
    // park h_bar (scaled) in LDS f64 view; acc DIES here
    double2* park2 = (double2*)buf.d;
#pragma unroll
    for (int si = 0; si < 2; ++si)
#pragma unroll
      for (int i = 0; i < 4; ++i) {
        double2 r2 = ((const double2*)rden)[(i << 6) + lane];
        double2 v;
        v.x = acc[si][i * 2]     * r2.x;
        v.y = acc[si][i * 2 + 1] * r2.y;
        park2[(size_t)(wv * 2 + si) * 256 + (i << 6) + lane] = v;
      }
  }

  // ---- phase 2: OMP, one wave per signal (2 sequential per wave)
#pragma unroll
  for (int si = 0; si < 2; ++si) {
    const int sig = wv * 2 + si, m = m0 + sig;
    const double*  hbs = buf.d + (size_t)sig * NA;            // parked h_bar
    const double2* hb2 = (const double2*)buf.d + (size_t)sig * 256;
    double h8[8];
#pragma unroll
    for (int i = 0; i < 4; ++i) {          // h(0) = h_bar, from LDS
      double2 hv = hb2[(i << 6) + lane];
      h8[i * 2] = hv.x; h8[i * 2 + 1] = hv.y;
    }
    unsigned msk = 0xFFu;
    int I[KS];
    double Lm[15], rd[KS], gam[KS], hbI[KS];

    omp_step<0>(lane, G, hbs, hb2, h8, msk, I, Lm, rd, gam, hbI);
    omp_step<1>(lane, G, hbs, hb2, h8, msk, I, Lm, rd, gam, hbI);
    omp_step<2>(lane, G, hbs, hb2, h8, msk, I, Lm, rd, gam, hbI);
    omp_step<3>(lane, G, hbs, hb2, h8, msk, I, Lm, rd, gam, hbI);
    omp_step<4>(lane, G, hbs, hb2, h8, msk, I, Lm, rd, gam, hbI);

    // ---- epilogue for this signal
    double r = 0.0;
#pragma unroll
    for (int j = 0; j < KS; ++j) r += gam[j] * DnT[(size_t)I[j] * NC + lane];
    const double e = (double)((si == 0) ? xf0 : xf1);
    const double d = r - e;                      // z_dl - z_e
    xsz[lane * 8 + sig] = (float)(e + d);        // zout[c=lane][s=sig]
    double sq = d * d;
#pragma unroll
    for (int off = 1; off < 64; off <<= 1) sq += __shfl_xor(sq, off);
    if (lane == 0) wsq[sig] = sq;

    // support / coeffs: constant-index selection chains only
    if (lane < KS) {
      int    iv = I[0];
      double gv = gam[0];
      if (lane == 1) { iv = I[1]; gv = gam[1]; }
      if (lane == 2) { iv = I[2]; gv = gam[2]; }
      if (lane == 3) { iv = I[3]; gv = gam[3]; }
      if (lane == 4) { iv = I[4]; gv = gam[4]; }
      out[OUT_SUP + (size_t)m * KS + lane] = (float)iv;
      out[OUT_COF + (size_t)m * KS + lane] = (float)gv;
    }
  }

  __syncthreads();
  // coalesced z_dl store from zout (xsz[c*8+s])
  for (int j = t; j < 8 * NC; j += 256) {
    int c = j >> 3, s = j & 7;
    out[zbase + (size_t)c * 4096 + s] = xsz[j];
  }
  if (t == 0) {
    double ssum = 0.0;
#pragma unroll
    for (int i = 0; i < 8; ++i) ssum += wsq[i];
    atomicAdd(accum, ssum);
  }
}

__global__ void final_kernel(const double* __restrict__ accum, float* __restrict__ out) {
  double mse = *accum / 2097152.0;
  out[OUT_LOSS] = (float)(mse + 0.25 * mse);
}

extern "C" void kernel_launch(void* const* d_in, const int* in_sizes, int n_in,
                              void* d_out, int out_size, void* d_ws, size_t ws_size,
                              hipStream_t stream) {
  const float* z_e = (const float*)d_in[0];
  const float* dic = (const float*)d_in[1];
  float* out = (float*)d_out;
  double* ws = (double*)d_ws;
  double* Dn   = ws + WS_DN;
  double* DnT  = ws + WS_DNT;
  double* G    = ws + WS_G;
  double* rden = ws + WS_RDEN;
  double* accu = ws + WS_ACC;

  hipLaunchKernelGGL(norm_kernel,  dim3(1),    dim3(512), 0, stream, dic, Dn, DnT, rden);
  hipLaunchKernelGGL(gram_kernel,  dim3(NA),   dim3(NA),  0, stream, Dn, G, accu);
  hipLaunchKernelGGL(omp_kernel,   dim3(4096), dim3(256), 0, stream,
                     z_e, dic, DnT, G, rden, out, accu);
  hipLaunchKernelGGL(final_kernel, dim3(1),    dim3(1),   0, stream, accu, out);
}